// Round 4
// baseline (76.563 us; speedup 1.0000x reference)
//
#include <hip/hip_runtime.h>

typedef __attribute__((ext_vector_type(8))) short bf16x8;
typedef __attribute__((ext_vector_type(4))) short s16x4;
typedef __attribute__((ext_vector_type(4))) float f32x4;
typedef __attribute__((ext_vector_type(4))) int   i32x4;

#define MFMA16 __builtin_amdgcn_mfma_f32_16x16x32_bf16

#define B_ 64
#define N_ 512
#define D_ 128
#define NCHK 16        // chunks of 32 keys
#define BUFB 16384     // bytes per LDS buffer: K 8KB + V 8KB

__device__ __forceinline__ unsigned short f2bf(float f) {
  unsigned u = __builtin_bit_cast(unsigned, f);
  u += 0x7fffu + ((u >> 16) & 1u);          // round-to-nearest-even
  return (unsigned short)(u >> 16);
}
__device__ __forceinline__ int packbf2(float lo, float hi) {
  return (int)((unsigned)f2bf(lo) | ((unsigned)f2bf(hi) << 16));
}

__device__ __forceinline__ void gload_lds16(const void* g, void* l) {
  __builtin_amdgcn_global_load_lds((const __attribute__((address_space(1))) unsigned*)g,
                                   (__attribute__((address_space(3))) unsigned*)l, 16, 0, 0);
}

// ---------------- W -> bf16 prep ----------------
__global__ void prep_w(const float* __restrict__ Wk, const float* __restrict__ Wq,
                       short* __restrict__ wkb, short* __restrict__ wqb) {
  int i = blockIdx.x * 256 + threadIdx.x;
  if (i < D_ * D_) { wkb[i] = (short)f2bf(Wk[i]); wqb[i] = (short)f2bf(Wq[i]); }
}

// ---------------- projections: k = h@Wk^T+bk, q = h@Wq^T+bq (bf16 out, + kT) ----------------
__global__ __launch_bounds__(256, 2) void proj_kernel(
    const float* __restrict__ h1, const float* __restrict__ h2,
    const short* __restrict__ wkb, const short* __restrict__ wqb,
    const float* __restrict__ bk, const float* __restrict__ bq,
    short* __restrict__ k1, short* __restrict__ k2,
    short* __restrict__ q1, short* __restrict__ q2,
    short* __restrict__ k1T, short* __restrict__ k2T) {
  const int wave = threadIdx.x >> 6, lane = threadIdx.x & 63;
  const int c = lane & 15, g = lane >> 4;
  const int rw = blockIdx.x * 128 + wave * 32;
  const int inp = rw >> 15;
  const int loc = rw & 32767;
  const int b = loc >> 9, n0 = loc & 511;
  const float* __restrict__ h = inp ? h2 : h1;
  short* __restrict__ kout = inp ? k2 : k1;
  short* __restrict__ qout = inp ? q2 : q1;
  short* __restrict__ kT   = inp ? k2T : k1T;

  bf16x8 xf[2][4];
#pragma unroll
  for (int mt = 0; mt < 2; ++mt) {
    const float* hr = h + (long)(loc + mt * 16 + c) * D_;
#pragma unroll
    for (int kk = 0; kk < 4; ++kk) {
      f32x4 lo = *(const f32x4*)(hr + kk * 32 + g * 8);
      f32x4 hi = *(const f32x4*)(hr + kk * 32 + g * 8 + 4);
      bf16x8 v;
      v[0] = (short)f2bf(lo[0]); v[1] = (short)f2bf(lo[1]);
      v[2] = (short)f2bf(lo[2]); v[3] = (short)f2bf(lo[3]);
      v[4] = (short)f2bf(hi[0]); v[5] = (short)f2bf(hi[1]);
      v[6] = (short)f2bf(hi[2]); v[7] = (short)f2bf(hi[3]);
      xf[mt][kk] = v;
    }
  }

#pragma unroll
  for (int et = 0; et < 8; ++et) {
    bf16x8 wkf[4], wqf[4];
    const short* wkr = wkb + (et * 16 + c) * D_;
    const short* wqr = wqb + (et * 16 + c) * D_;
#pragma unroll
    for (int kk = 0; kk < 4; ++kk) {
      wkf[kk] = *(const bf16x8*)(wkr + kk * 32 + g * 8);
      wqf[kk] = *(const bf16x8*)(wqr + kk * 32 + g * 8);
    }
    f32x4 ak[2], aq[2], at[2];
#pragma unroll
    for (int mt = 0; mt < 2; ++mt) {
      ak[mt] = (f32x4){0.f, 0.f, 0.f, 0.f};
      aq[mt] = (f32x4){0.f, 0.f, 0.f, 0.f};
      at[mt] = (f32x4){0.f, 0.f, 0.f, 0.f};
    }
#pragma unroll
    for (int kk = 0; kk < 4; ++kk) {
#pragma unroll
      for (int mt = 0; mt < 2; ++mt) {
        ak[mt] = MFMA16(wkf[kk], xf[mt][kk], ak[mt], 0, 0, 0);
        aq[mt] = MFMA16(wqf[kk], xf[mt][kk], aq[mt], 0, 0, 0);
        at[mt] = MFMA16(xf[mt][kk], wkf[kk], at[mt], 0, 0, 0);
      }
    }
    f32x4 bkv = *(const f32x4*)(bk + et * 16 + g * 4);
    f32x4 bqv = *(const f32x4*)(bq + et * 16 + g * 4);
    float bks = bk[et * 16 + c];
#pragma unroll
    for (int mt = 0; mt < 2; ++mt) {
      s16x4 pk, pq, pt;
#pragma unroll
      for (int j = 0; j < 4; ++j) {
        pk[j] = (short)f2bf(ak[mt][j] + bkv[j]);
        pq[j] = (short)f2bf(aq[mt][j] + bqv[j]);
        pt[j] = (short)f2bf(at[mt][j] + bks);
      }
      long row = (long)(loc + mt * 16 + c);
      *(s16x4*)(kout + row * D_ + et * 16 + g * 4) = pk;
      *(s16x4*)(qout + row * D_ + et * 16 + g * 4) = pq;
      *(s16x4*)(kT + ((long)(b * D_ + et * 16 + c)) * N_ + n0 + mt * 16 + g * 4) = pt;
    }
  }
}

// ---------------- attention: flash-style online softmax ----------------
// grid 1024 x 128 thr: wgid = qt*128 + (dir*64 + b); stride-128 keeps all 8
// q-tiles of one (b,dir) on one XCD. 2 waves x 32 q-rows (2x16 tiles).
// Chunk = 32 keys: K [32][256B] + V [128][64B] staged (XOR-swizzled) in one
// 16KB buffer, double-buffered; per chunk: QK^T -> online softmax (defer-max)
// -> P->bf16 -> PV.
__global__ __launch_bounds__(128, 2) void attn_kernel(
    const short* __restrict__ k1, const short* __restrict__ k2,
    const short* __restrict__ q1, const short* __restrict__ q2,
    const short* __restrict__ k1T, const short* __restrict__ k2T,
    const float* __restrict__ tptr,
    const int* __restrict__ len1, const int* __restrict__ len2,
    float* __restrict__ out) {
  __shared__ char smem[2 * BUFB];
  const int tid = threadIdx.x;
  const int wave = tid >> 6, lane = tid & 63;
  const int c = lane & 15, g = lane >> 4;
  const int wgid = blockIdx.x;
  const int qt = wgid >> 7;
  const int bd = wgid & 127;
  const int dir = bd >> 6, b = bd & 63;
  const short* __restrict__ qp = dir ? q2 : q1;
  const short* __restrict__ kp = dir ? k1 : k2;
  const short* __restrict__ vT = dir ? k1T : k2T;
  const int lk = dir ? len1[b] : len2[b];
  const int lq = dir ? len2[b] : len1[b];
  float* __restrict__ o = out + (long)dir * B_ * N_ * D_;
  const float ts = *tptr;
  const int q0 = qt * 64 + wave * 32;

  const char* kbase = (const char*)(kp + (long)b * N_ * D_);   // [512][256B]
  const char* vbase = (const char*)(vT + (long)b * D_ * N_);   // [128][1024B]

  // stage chunk i: K rows [i*32,+32) x 256B at [0,8K); V 128 rows x 64B
  // (byte-cols i*64..+64) at [8K,16K). Linear LDS dest, inverse-swizzled src.
  auto stage = [&](int i) {
    char* buf = smem + BUFB * (i & 1);
#pragma unroll
    for (int j = 0; j < 4; ++j) {          // K: 4 passes x 2KB
      int L = j * 2048 + tid * 16;
      int row = L >> 8, off = L & 255;
      const char* gp = kbase + (i * 32 + row) * 256 + (off ^ ((row & 7) << 4));
      gload_lds16(gp, buf + j * 2048 + (wave << 10));
    }
#pragma unroll
    for (int j = 0; j < 4; ++j) {          // V: 4 passes x 2KB
      int L = j * 2048 + tid * 16;
      int row = L >> 6, off = L & 63;
      const char* gp = vbase + row * 1024 + i * 64 + (off ^ (((row >> 1) & 3) << 4));
      gload_lds16(gp, buf + 8192 + j * 2048 + (wave << 10));
    }
  };

  // Q fragments for 2 q-tiles (lane=q-row)
  bf16x8 qf[2][4];
#pragma unroll
  for (int t = 0; t < 2; ++t) {
    const short* qrow = qp + ((long)(b * N_ + q0 + t * 16 + c)) * D_;
#pragma unroll
    for (int kk = 0; kk < 4; ++kk) qf[t][kk] = *(const bf16x8*)(qrow + kk * 32 + g * 8);
  }

  f32x4 oacc[2][8];
#pragma unroll
  for (int t = 0; t < 2; ++t)
#pragma unroll
    for (int dt = 0; dt < 8; ++dt) oacc[t][dt] = (f32x4){0.f, 0.f, 0.f, 0.f};
  float m[2] = {-3e38f, -3e38f};
  float l[2] = {0.f, 0.f};

  const int srcA = c + ((g & 1) << 5);
  const int srcB = srcA + 16;
  const bool lowhalf = (g < 2);

  stage(0);

#pragma unroll 2
  for (int ch = 0; ch < NCHK; ++ch) {
    asm volatile("s_waitcnt vmcnt(0)" ::: "memory");   // stage(ch) landed
    __builtin_amdgcn_sched_barrier(0);
    __builtin_amdgcn_s_barrier();                      // both waves ready; prev buf free
    __builtin_amdgcn_sched_barrier(0);
    if (ch + 1 < NCHK) stage(ch + 1);                  // DMA hides under compute below
    const char* buf = smem + BUFB * (ch & 1);

    // ---- QK^T: 8 K-frag reads, 16 MFMA ----
    f32x4 sv[2][2];
    __builtin_amdgcn_s_setprio(1);
#pragma unroll
    for (int tl = 0; tl < 2; ++tl) {
      int r = tl * 16 + c;
      const char* base = buf + (r << 8);
      int sw = (r & 7) << 4;
      f32x4 a0 = (f32x4){0.f, 0.f, 0.f, 0.f};
      f32x4 a1 = (f32x4){0.f, 0.f, 0.f, 0.f};
#pragma unroll
      for (int kk = 0; kk < 4; ++kk) {
        bf16x8 kf = *(const bf16x8*)(base + ((kk * 64 + g * 16) ^ sw));
        a0 = MFMA16(kf, qf[0][kk], a0, 0, 0, 0);
        a1 = MFMA16(kf, qf[1][kk], a1, 0, 0, 0);
      }
      sv[0][tl] = a0; sv[1][tl] = a1;
    }
    __builtin_amdgcn_s_setprio(0);

    // ---- online softmax per q-tile ----
    bf16x8 pf[2];
#pragma unroll
    for (int t = 0; t < 2; ++t) {
      float pmax = -3e38f;
#pragma unroll
      for (int tl = 0; tl < 2; ++tl) {
        const int node = ch * 32 + tl * 16 + g * 4;
#pragma unroll
        for (int j = 0; j < 4; ++j) {
          float v = sv[t][tl][j] * ts;
          v = (node + j < lk) ? v : -1e9f;
          sv[t][tl][j] = v;
          pmax = fmaxf(pmax, v);
        }
      }
      pmax = fmaxf(pmax, __shfl_xor(pmax, 16));
      pmax = fmaxf(pmax, __shfl_xor(pmax, 32));
      if (!__all(pmax - m[t] <= 8.0f)) {               // defer-max (T13)
        float newm = fmaxf(m[t], pmax);
        float sc = __expf(m[t] - newm);
        m[t] = newm;
        l[t] *= sc;
#pragma unroll
        for (int dt = 0; dt < 8; ++dt)
#pragma unroll
          for (int j = 0; j < 4; ++j) oacc[t][dt][j] *= sc;
      }
      float sum = 0.f;
#pragma unroll
      for (int tl = 0; tl < 2; ++tl)
#pragma unroll
        for (int j = 0; j < 4; ++j) {
          float p = __expf(sv[t][tl][j] - m[t]);
          sv[t][tl][j] = p;
          sum += p;
        }
      sum += __shfl_xor(sum, 16);
      sum += __shfl_xor(sum, 32);
      l[t] += sum;

      // pack P -> bf16 B-fragment (keys g*8..g*8+7 of the 32-key chunk)
      int a0 = packbf2(sv[t][0][0], sv[t][0][1]);
      int a1 = packbf2(sv[t][0][2], sv[t][0][3]);
      int b0 = packbf2(sv[t][1][0], sv[t][1][1]);
      int b1 = packbf2(sv[t][1][2], sv[t][1][3]);
      int xa0 = __shfl(a0, srcA), xb0 = __shfl(b0, srcA);
      int xa1 = __shfl(a1, srcA), xb1 = __shfl(b1, srcA);
      int ya0 = __shfl(a0, srcB), yb0 = __shfl(b0, srcB);
      int ya1 = __shfl(a1, srcB), yb1 = __shfl(b1, srcB);
      i32x4 ui;
      ui[0] = lowhalf ? xa0 : xb0;
      ui[1] = lowhalf ? xa1 : xb1;
      ui[2] = lowhalf ? ya0 : yb0;
      ui[3] = lowhalf ? ya1 : yb1;
      pf[t] = __builtin_bit_cast(bf16x8, ui);
    }

    // ---- PV: 8 V-frag reads, 16 MFMA ----
    __builtin_amdgcn_s_setprio(1);
#pragma unroll
    for (int dt = 0; dt < 8; ++dt) {
      int row = dt * 16 + c;
      const char* vb = buf + 8192 + row * 64;
      bf16x8 vt = *(const bf16x8*)(vb + ((g * 16) ^ (((row >> 1) & 3) << 4)));
      oacc[0][dt] = MFMA16(vt, pf[0], oacc[0][dt], 0, 0, 0);
      oacc[1][dt] = MFMA16(vt, pf[1], oacc[1][dt], 0, 0, 0);
    }
    __builtin_amdgcn_s_setprio(0);
  }

  // ---- epilogue: o = oacc / l, zero invalid q-rows ----
#pragma unroll
  for (int t = 0; t < 2; ++t) {
    const int qg = q0 + t * 16 + c;
    const bool valid = qg < lq;
    const float rinv = 1.0f / l[t];
    float* orow = o + ((long)(b * N_ + qg)) * D_;
#pragma unroll
    for (int dt = 0; dt < 8; ++dt) {
      f32x4 vo;
#pragma unroll
      for (int j = 0; j < 4; ++j) vo[j] = valid ? oacc[t][dt][j] * rinv : 0.0f;
      *(f32x4*)(orow + dt * 16 + g * 4) = vo;
    }
  }
}

extern "C" void kernel_launch(void* const* d_in, const int* in_sizes, int n_in,
                              void* d_out, int out_size, void* d_ws, size_t ws_size,
                              hipStream_t stream) {
  const float* h1 = (const float*)d_in[0];
  const float* h2 = (const float*)d_in[1];
  const float* Wk = (const float*)d_in[2];
  const float* bk = (const float*)d_in[3];
  const float* Wq = (const float*)d_in[4];
  const float* bq = (const float*)d_in[5];
  const float* t  = (const float*)d_in[6];
  const int* len1 = (const int*)d_in[7];
  const int* len2 = (const int*)d_in[8];

  char* ws = (char*)d_ws;
  const size_t SZ = (size_t)B_ * N_ * D_ * 2;
  short* k1  = (short*)(ws + 0 * SZ);
  short* k2  = (short*)(ws + 1 * SZ);
  short* q1  = (short*)(ws + 2 * SZ);
  short* q2  = (short*)(ws + 3 * SZ);
  short* k1T = (short*)(ws + 4 * SZ);
  short* k2T = (short*)(ws + 5 * SZ);
  short* wkb = (short*)(ws + 6 * SZ);
  short* wqb = (short*)(ws + 6 * SZ + D_ * D_ * 2);

  prep_w<<<64, 256, 0, stream>>>(Wk, Wq, wkb, wqb);
  proj_kernel<<<512, 256, 0, stream>>>(h1, h2, wkb, wqb, bk, bq,
                                       k1, k2, q1, q2, k1T, k2T);
  attn_kernel<<<1024, 128, 0, stream>>>(k1, k2, q1, q2, k1T, k2T,
                                        t, len1, len2, (float*)d_out);
}